// Round 22
// baseline (149.985 us; speedup 1.0000x reference)
//
#include <hip/hip_runtime.h>
#include <stdint.h>

typedef unsigned short u16;
typedef __bf16 bf16x8 __attribute__((ext_vector_type(8)));
typedef float f32x4 __attribute__((ext_vector_type(4)));

#define QSCALE (19.5f/1024.0f * 1.44269504088896340736f)
// float-magic Schraudolph: y = fma(s,128, 2^23*1.5 + 16250) -> low16(bits(y)) = bf16bits(exp2(s))
#define EXPMAGIC 12599162.0f

__device__ __forceinline__ u16 f2bf(float f){
  uint32_t u = __float_as_uint(f);
  return (u16)((u + 0x7FFFu + ((u >> 16) & 1u)) >> 16);   // RNE
}

__device__ __forceinline__ uint64_t cvt4(float4 f){
  union{ u16 u[4]; uint64_t v; } pk;
  pk.u[0]=f2bf(f.x); pk.u[1]=f2bf(f.y); pk.u[2]=f2bf(f.z); pk.u[3]=f2bf(f.w);
  return pk.v;
}

#define GLD_LDS16(g,l) __builtin_amdgcn_global_load_lds( \
    (const __attribute__((address_space(1))) void*)(g),  \
    (__attribute__((address_space(3))) void*)(l), 16, 0, 0)

// ---------------- fused prep ----------------
__global__ __launch_bounds__(256) void k_prep(
    const float4* __restrict__ x,  const float4* __restrict__ Wq,
    const float4* __restrict__ Wk, const float4* __restrict__ Wv,
    const float4* __restrict__ Wo,
    const float4* __restrict__ bq, const float4* __restrict__ bk, const float4* __restrict__ bv,
    uint64_t* __restrict__ xb, uint64_t* __restrict__ wqkv, uint64_t* __restrict__ wob,
    float4* __restrict__ bqkv)
{
  const int NX = 2097152, NW = 262144;
  const int total = NX + 4*NW + 768;
  int i = blockIdx.x*256 + threadIdx.x;
  const int stride = gridDim.x*256;
  for (; i < total; i += stride){
    if (i < NX)             xb[i] = cvt4(x[i]);
    else if (i < NX+NW)     { int j = i-NX;      wqkv[j]      = cvt4(Wq[j]); }
    else if (i < NX+2*NW)   { int j = i-NX-NW;   wqkv[NW+j]   = cvt4(Wk[j]); }
    else if (i < NX+3*NW)   { int j = i-NX-2*NW; wqkv[2*NW+j] = cvt4(Wv[j]); }
    else if (i < NX+4*NW)   { int j = i-NX-3*NW; wob[j]       = cvt4(Wo[j]); }
    else {
      int j = i - NX - 4*NW;
      bqkv[j] = (j < 256) ? bq[j] : (j < 512 ? bk[j-256] : bv[j-512]);
    }
  }
}

// ---------------- 128x256 bf16 GEMM: 8 waves (2Mx4N), wave-tile 64x64 ----------------
// BK=32, 3-ring (72KB -> 2 blocks/CU), stage-2-ahead, counted vmcnt(3).
// Schedule: stage(t+2) -> ds_read(t) -> vmcnt+barrier -> MFMA(t)  (MFMA off the barrier path).
// XCD-chunked grid (1D): xcd=flat&7, idx=flat>>3; mt=xcd*8+(idx&7); nt=idx>>3.
// MODE 0: QKV projection (768 blocks); V^T written in bijection-order n'.
// MODE 1: output projection -> fp32 (256 blocks).
// Balanced swizzle: LDS[row][c] = global[row][c ^ ((row>>1)&3)].
template<int MODE>
__global__ __launch_bounds__(512) void gemm128x256(
    const u16* __restrict__ A, const u16* __restrict__ Bw,
    const float* __restrict__ bias, float* __restrict__ Cout,
    u16* __restrict__ q_ws, u16* __restrict__ k_ws, u16* __restrict__ v_ws)
{
  __shared__ u16 lds[3*12288];   // [buf:3][ A:128x32 (4096 u16) | B:256x32 (8192 u16) ]
  const int tid  = threadIdx.x;
  const int w    = tid >> 6, lane = tid & 63;
  const int wr   = w >> 2,  wc   = w & 3;
  const int g    = lane >> 4, c16 = lane & 15;

  const int flat = blockIdx.x;
  const int xcd  = flat & 7, idx = flat >> 3;
  const int mt   = xcd*8 + (idx & 7);
  const int nt   = idx >> 3;
  const size_t arow0 = (size_t)mt * 128, brow0 = (size_t)nt * 256;

  f32x4 acc[4][4] = {};

  const int schk = ((tid & 3) ^ ((tid >> 3) & 3)) * 8;
  const u16* gA = A  + (arow0 + (tid >> 2))*1024 + schk;
  const u16* gB = Bw + (brow0 + (tid >> 2))*1024 + schk;

  const int rswz = (g ^ ((c16 >> 1) & 3)) * 8;
  const int abase = (wr*64 + c16)*32 + rswz;
  const int bbase = 4096 + (wc*64 + c16)*32 + rswz;

#define GSTAGE(B2) do{ \
    GLD_LDS16(gA,           &lds[(B2)*12288 +        tid*8]); \
    GLD_LDS16(gB,           &lds[(B2)*12288 + 4096 + tid*8]); \
    GLD_LDS16(gB + 131072,  &lds[(B2)*12288 + 8192 + tid*8]); \
    gA += 32; gB += 32; \
  }while(0)

#define GBODY(B, STG, VMW) do{ \
    if (STG) GSTAGE(((B)+2)%3); \
    bf16x8 af[4], bfr[4]; \
    _Pragma("unroll") \
    for (int m = 0; m < 4; m++) \
      af[m]  = __builtin_bit_cast(bf16x8, *(const uint4*)(&lds[(B)*12288 + abase + m*512])); \
    _Pragma("unroll") \
    for (int n = 0; n < 4; n++) \
      bfr[n] = __builtin_bit_cast(bf16x8, *(const uint4*)(&lds[(B)*12288 + bbase + n*512])); \
    if ((VMW) == 3){ asm volatile("s_waitcnt vmcnt(3)" ::: "memory"); __builtin_amdgcn_s_barrier(); } \
    else if ((VMW) == 0){ asm volatile("s_waitcnt vmcnt(0)" ::: "memory"); __builtin_amdgcn_s_barrier(); } \
    __builtin_amdgcn_s_setprio(1); \
    _Pragma("unroll") \
    for (int m = 0; m < 4; m++) \
      _Pragma("unroll") \
      for (int n = 0; n < 4; n++) \
        acc[m][n] = __builtin_amdgcn_mfma_f32_16x16x32_bf16(af[m], bfr[n], acc[m][n], 0, 0, 0); \
    __builtin_amdgcn_s_setprio(0); \
  }while(0)

  GSTAGE(0); GSTAGE(1);
  asm volatile("s_waitcnt vmcnt(3)" ::: "memory");
  __builtin_amdgcn_s_barrier();

  #pragma unroll 1
  for (int rr = 0; rr < 10; rr++){
    GBODY(0, 1, 3);
    GBODY(1, 1, 3);
    GBODY(2, 1, 3);
  }
  GBODY(0, 0, 0);
  GBODY(1, 0, -1);

#undef GBODY
#undef GSTAGE

  #pragma unroll
  for (int m = 0; m < 4; m++){
    const size_t i0 = arow0 + wr*64 + m*16 + g*4;
    #pragma unroll
    for (int n = 0; n < 4; n++){
      const int o = (int)brow0 + wc*64 + n*16 + c16;
      const float bias_v = bias[o];
      if (MODE == 0){
        const int proj = o >> 10, wi = o & 1023, hh = wi >> 6, dd = wi & 63;
        if (proj < 2){
          u16* base = (proj == 0) ? q_ws : k_ws;
          const float sc = (proj == 0) ? QSCALE : 1.0f;
          #pragma unroll
          for (int r = 0; r < 4; r++){
            const size_t i = i0 + r;
            const size_t bb = i >> 11, nn = i & 2047;
            base[((bb*16 + hh)*2048 + nn)*64 + dd] = f2bf((acc[m][n][r] + bias_v)*sc);
          }
        } else {
          // V^T in bijection-order: n' = (nn & ~31) | ((nn>>4)&1)<<2 | ((nn>>2)&3)<<3
          const size_t bb = i0 >> 11;
          const uint32_t nn = (uint32_t)(i0 & 2047);
          const uint32_t nnp = (nn & ~31u) | (((nn >> 4) & 1u) << 2) | (((nn >> 2) & 3u) << 3);
          union{ u16 u[4]; uint64_t v; } pk;
          #pragma unroll
          for (int r = 0; r < 4; r++) pk.u[r] = f2bf(acc[m][n][r] + bias_v);
          *reinterpret_cast<uint64_t*>(v_ws + ((bb*16 + hh)*64 + dd)*2048 + nnp) = pk.v;
        }
      } else {
        #pragma unroll
        for (int r = 0; r < 4; r++)
          Cout[(i0 + r)*1024 + o] = acc[m][n][r] + bias_v;
      }
    }
  }
}

// ---------------- flash attention: 4-ring, paired tiles; V reads single b128 ----------------
__global__ __launch_bounds__(256, 2) void attn_k(
    const u16* __restrict__ Q, const u16* __restrict__ Kb, const u16* __restrict__ Vt,
    u16* __restrict__ O)
{
  __shared__ u16 lds[4*8192];   // [buf:4][ K:4096 | V:4096 ], XOR-8 swizzled 16B slots
  const int tid = threadIdx.x, w = tid >> 6, lane = tid & 63;
  const int g = lane >> 4, l16 = lane & 15;

  const int f   = ((blockIdx.x & 7) << 6) | (blockIdx.x >> 3);
  const int qt_ = f & 7, bh = f >> 3;
  const int b = bh >> 4, h = bh & 15;
  const size_t hb = (size_t)bh * 2048 * 64;

  const int qrow0 = qt_*256 + w*64 + l16;
  bf16x8 qf[4][2];
  #pragma unroll
  for (int qt = 0; qt < 4; qt++)
    #pragma unroll
    for (int kc = 0; kc < 2; kc++)
      qf[qt][kc] = __builtin_bit_cast(bf16x8,
        *(const uint4*)(Q + hb + (size_t)(qrow0 + qt*16)*64 + kc*32 + g*8));

  f32x4 acc[4][4] = {};
  f32x4 lacc[4] = {};

  union{ u16 u[8]; bf16x8 f; } one_;
  #pragma unroll
  for (int i = 0; i < 8; i++) one_.u[i] = 0x3F80;
  const bf16x8 onesv = one_.f;

  const int srowL = w*8 + (lane >> 3);
  const int schunk = ((lane & 7) ^ ((lane >> 3) & 7)) * 8;
  const u16* gKs = Kb + hb + (size_t)srowL*64   + schunk;
  const u16* gVs = Vt + hb + (size_t)srowL*2048 + schunk;

  u16* ldsK0 = &lds[w*512];
  u16* ldsV0 = &lds[4096 + w*512];

  const int kb0 = l16*64 + (g ^ (l16 & 7))*8;
  const int kb1 = kb0 ^ 32;
  // V fragment (bijection-order layout): single b128 at chunk (p*4+g)^(l16&7)
  int vbp[2];
  #pragma unroll
  for (int p = 0; p < 2; p++)
    vbp[p] = l16*64 + (((p*4 + g) ^ (l16 & 7)) << 3);

#define STAGE_T(B2) do{ \
    GLD_LDS16(gKs,          ldsK0 + (B2)*8192); \
    GLD_LDS16(gKs + 2048,   ldsK0 + (B2)*8192 + 2048); \
    GLD_LDS16(gVs,          ldsV0 + (B2)*8192); \
    GLD_LDS16(gVs + 65536,  ldsV0 + (B2)*8192 + 2048); \
    gKs += 4096; gVs += 64; \
  }while(0)

#define TILE_T(B) do{ \
    _Pragma("unroll") \
    for (int p = 0; p < 2; p++){ \
      uint32_t pklo[2][4], pkhi[2][4]; \
      _Pragma("unroll") \
      for (int jh = 0; jh < 2; jh++){ \
        const int jt = p*2 + jh; \
        bf16x8 kf0 = __builtin_bit_cast(bf16x8, *(const uint4*)(&lds[(B)*8192 + jt*1024] + kb0)); \
        bf16x8 kf1 = __builtin_bit_cast(bf16x8, *(const uint4*)(&lds[(B)*8192 + jt*1024] + kb1)); \
        _Pragma("unroll") \
        for (int qt = 0; qt < 4; qt++){ \
          f32x4 st = {0.f,0.f,0.f,0.f}; \
          st = __builtin_amdgcn_mfma_f32_16x16x32_bf16(kf0, qf[qt][0], st, 0, 0, 0); \
          st = __builtin_amdgcn_mfma_f32_16x16x32_bf16(kf1, qf[qt][1], st, 0, 0, 0); \
          const uint32_t y0 = __float_as_uint(fmaf(st[0], 128.f, EXPMAGIC)); \
          const uint32_t y1 = __float_as_uint(fmaf(st[1], 128.f, EXPMAGIC)); \
          const uint32_t y2 = __float_as_uint(fmaf(st[2], 128.f, EXPMAGIC)); \
          const uint32_t y3 = __float_as_uint(fmaf(st[3], 128.f, EXPMAGIC)); \
          pklo[jh][qt] = __builtin_amdgcn_perm(y1, y0, 0x05040100u); \
          pkhi[jh][qt] = __builtin_amdgcn_perm(y3, y2, 0x05040100u); \
        } \
      } \
      union { uint32_t u[4]; bf16x8 f; } pf[4]; \
      _Pragma("unroll") \
      for (int qt = 0; qt < 4; qt++){ \
        pf[qt].u[0] = pklo[0][qt]; pf[qt].u[1] = pkhi[0][qt]; \
        pf[qt].u[2] = pklo[1][qt]; pf[qt].u[3] = pkhi[1][qt]; \
      } \
      __builtin_amdgcn_s_setprio(1); \
      _Pragma("unroll") \
      for (int qt = 0; qt < 4; qt++) \
        lacc[qt] = __builtin_amdgcn_mfma_f32_16x16x32_bf16(onesv, pf[qt].f, lacc[qt], 0, 0, 0); \
      _Pragma("unroll") \
      for (int dt = 0; dt < 4; dt++){ \
        union { uint4 u4; bf16x8 f; } vf; \
        vf.u4 = *(const uint4*)(&lds[(B)*8192 + 4096 + dt*1024] + vbp[p]); \
        _Pragma("unroll") \
        for (int qt = 0; qt < 4; qt++) \
          acc[dt][qt] = __builtin_amdgcn_mfma_f32_16x16x32_bf16(vf.f, pf[qt].f, acc[dt][qt], 0, 0, 0); \
      } \
      __builtin_amdgcn_s_setprio(0); \
    } \
  }while(0)

#define PAIR_T(B0, B1, STG, SYNC) do{ \
    if (STG){ STAGE_T((B0)^2); STAGE_T((B1)^2); } \
    TILE_T(B0); \
    TILE_T(B1); \
    if (SYNC){ asm volatile("s_waitcnt vmcnt(0)" ::: "memory"); __builtin_amdgcn_s_barrier(); } \
  }while(0)

  STAGE_T(0); STAGE_T(1);
  asm volatile("s_waitcnt vmcnt(0)" ::: "memory");
  __builtin_amdgcn_s_barrier();

  #pragma unroll 1
  for (int rr = 0; rr < 7; rr++){
    PAIR_T(0, 1, 1, 1);
    PAIR_T(2, 3, 1, 1);
  }
  PAIR_T(0, 1, 1, 1);
  PAIR_T(2, 3, 0, 0);

#undef PAIR_T
#undef TILE_T
#undef STAGE_T

  float inv[4];
  #pragma unroll
  for (int qt = 0; qt < 4; qt++) inv[qt] = 1.f / lacc[qt][0];

  #pragma unroll
  for (int qt = 0; qt < 4; qt++){
    const size_t ob = (((size_t)(b*2048 + qrow0 + qt*16))*16 + h)*64;
    #pragma unroll
    for (int dt = 0; dt < 4; dt++){
      union{ u16 u[4]; uint64_t v; } pkk;
      #pragma unroll
      for (int r = 0; r < 4; r++) pkk.u[r] = f2bf(acc[dt][qt][r] * inv[qt]);
      *reinterpret_cast<uint64_t*>(O + ob + dt*16 + g*4) = pkk.v;
    }
  }
}

// ---------------- launch ----------------
extern "C" void kernel_launch(void* const* d_in, const int* in_sizes, int n_in,
                              void* d_out, int out_size, void* d_ws, size_t ws_size,
                              hipStream_t stream)
{
  const float* x  = (const float*)d_in[0];
  const float* Wq = (const float*)d_in[1];
  const float* bq = (const float*)d_in[2];
  const float* Wk = (const float*)d_in[3];
  const float* bk = (const float*)d_in[4];
  const float* Wv = (const float*)d_in[5];
  const float* bv = (const float*)d_in[6];
  const float* Wo = (const float*)d_in[7];
  const float* bo = (const float*)d_in[8];
  float* out = (float*)d_out;

  char* ws = (char*)d_ws;
  size_t off = 0;
  auto bump = [&](size_t bytes){ size_t o = off; off = (off + bytes + 255) & ~(size_t)255; return o; };
  u16*  xb   = (u16*)  (ws + bump(8388608ull*2));
  u16*  wqkv = (u16*)  (ws + bump(3145728ull*2));
  u16*  wob  = (u16*)  (ws + bump(1048576ull*2));
  float* bqkv= (float*)(ws + bump(3072ull*4));
  u16*  qws  = (u16*)  (ws + bump(8388608ull*2));
  u16*  kws  = (u16*)  (ws + bump(8388608ull*2));
  u16*  vws  = (u16*)  (ws + bump(8388608ull*2));
  u16*  att  = (u16*)  (ws + bump(8388608ull*2));

  k_prep<<<2048, 256, 0, stream>>>(
      (const float4*)x, (const float4*)Wq, (const float4*)Wk, (const float4*)Wv, (const float4*)Wo,
      (const float4*)bq, (const float4*)bk, (const float4*)bv,
      (uint64_t*)xb, (uint64_t*)wqkv, (uint64_t*)wob, (float4*)bqkv);

  gemm128x256<0><<<768, 512, 0, stream>>>(xb, wqkv, bqkv, nullptr, qws, kws, vws);
  attn_k<<<512, 256, 0, stream>>>(qws, kws, vws, att);
  gemm128x256<1><<<256, 512, 0, stream>>>(att, wob, bo, out, nullptr, nullptr, nullptr);
}

// Round 23
// 148.023 us; speedup vs baseline: 1.0133x; 1.0133x over previous
//
#include <hip/hip_runtime.h>
#include <stdint.h>

typedef unsigned short u16;
typedef __bf16 bf16x8 __attribute__((ext_vector_type(8)));
typedef float f32x4 __attribute__((ext_vector_type(4)));

#define QSCALE (19.5f/1024.0f * 1.44269504088896340736f)
// float-magic Schraudolph: y = fma(s,128, 2^23*1.5 + 16250) -> low16(bits(y)) = bf16bits(exp2(s))
#define EXPMAGIC 12599162.0f

__device__ __forceinline__ u16 f2bf(float f){
  uint32_t u = __float_as_uint(f);
  return (u16)((u + 0x7FFFu + ((u >> 16) & 1u)) >> 16);   // RNE
}

__device__ __forceinline__ uint64_t cvt4(float4 f){
  union{ u16 u[4]; uint64_t v; } pk;
  pk.u[0]=f2bf(f.x); pk.u[1]=f2bf(f.y); pk.u[2]=f2bf(f.z); pk.u[3]=f2bf(f.w);
  return pk.v;
}

#define GLD_LDS16(g,l) __builtin_amdgcn_global_load_lds( \
    (const __attribute__((address_space(1))) void*)(g),  \
    (__attribute__((address_space(3))) void*)(l), 16, 0, 0)

// ---------------- fused prep ----------------
__global__ __launch_bounds__(256) void k_prep(
    const float4* __restrict__ x,  const float4* __restrict__ Wq,
    const float4* __restrict__ Wk, const float4* __restrict__ Wv,
    const float4* __restrict__ Wo,
    const float4* __restrict__ bq, const float4* __restrict__ bk, const float4* __restrict__ bv,
    uint64_t* __restrict__ xb, uint64_t* __restrict__ wqkv, uint64_t* __restrict__ wob,
    float4* __restrict__ bqkv)
{
  const int NX = 2097152, NW = 262144;
  const int total = NX + 4*NW + 768;
  int i = blockIdx.x*256 + threadIdx.x;
  const int stride = gridDim.x*256;
  for (; i < total; i += stride){
    if (i < NX)             xb[i] = cvt4(x[i]);
    else if (i < NX+NW)     { int j = i-NX;      wqkv[j]      = cvt4(Wq[j]); }
    else if (i < NX+2*NW)   { int j = i-NX-NW;   wqkv[NW+j]   = cvt4(Wk[j]); }
    else if (i < NX+3*NW)   { int j = i-NX-2*NW; wqkv[2*NW+j] = cvt4(Wv[j]); }
    else if (i < NX+4*NW)   { int j = i-NX-3*NW; wob[j]       = cvt4(Wo[j]); }
    else {
      int j = i - NX - 4*NW;
      bqkv[j] = (j < 256) ? bq[j] : (j < 512 ? bk[j-256] : bv[j-512]);
    }
  }
}

// ---------------- 128x256 bf16 GEMM: 8 waves (2Mx4N), wave-tile 64x64 ----------------
// BK=32, 3-ring (72KB -> 2 blocks/CU), stage-2-ahead, counted vmcnt(3).
// XCD-chunked grid (1D): xcd=flat&7, idx=flat>>3; mt=xcd*8+(idx&7); nt=idx>>3.
// MODE 0: QKV projection (768 blocks); V^T written in bijection-order n'
//   (n' = r | hi<<2 | g<<3 within each 32-run) so attn PV fragments are contiguous 16B.
// MODE 1: output projection -> fp32 (256 blocks).
// Balanced swizzle: LDS[row][c] = global[row][c ^ ((row>>1)&3)].
template<int MODE>
__global__ __launch_bounds__(512) void gemm128x256(
    const u16* __restrict__ A, const u16* __restrict__ Bw,
    const float* __restrict__ bias, float* __restrict__ Cout,
    u16* __restrict__ q_ws, u16* __restrict__ k_ws, u16* __restrict__ v_ws)
{
  __shared__ u16 lds[3*12288];   // [buf:3][ A:128x32 (4096 u16) | B:256x32 (8192 u16) ]
  const int tid  = threadIdx.x;
  const int w    = tid >> 6, lane = tid & 63;
  const int wr   = w >> 2,  wc   = w & 3;
  const int g    = lane >> 4, c16 = lane & 15;

  const int flat = blockIdx.x;
  const int xcd  = flat & 7, idx = flat >> 3;
  const int mt   = xcd*8 + (idx & 7);
  const int nt   = idx >> 3;
  const size_t arow0 = (size_t)mt * 128, brow0 = (size_t)nt * 256;

  f32x4 acc[4][4] = {};

  const int schk = ((tid & 3) ^ ((tid >> 3) & 3)) * 8;
  const u16* gA = A  + (arow0 + (tid >> 2))*1024 + schk;
  const u16* gB = Bw + (brow0 + (tid >> 2))*1024 + schk;

  const int rswz = (g ^ ((c16 >> 1) & 3)) * 8;
  const int abase = (wr*64 + c16)*32 + rswz;
  const int bbase = 4096 + (wc*64 + c16)*32 + rswz;

#define GSTAGE(B2) do{ \
    GLD_LDS16(gA,           &lds[(B2)*12288 +        tid*8]); \
    GLD_LDS16(gB,           &lds[(B2)*12288 + 4096 + tid*8]); \
    GLD_LDS16(gB + 131072,  &lds[(B2)*12288 + 8192 + tid*8]); \
    gA += 32; gB += 32; \
  }while(0)

#define GBODY(B, STG, VMW) do{ \
    if (STG) GSTAGE(((B)+2)%3); \
    bf16x8 af[4], bfr[4]; \
    _Pragma("unroll") \
    for (int m = 0; m < 4; m++) \
      af[m]  = __builtin_bit_cast(bf16x8, *(const uint4*)(&lds[(B)*12288 + abase + m*512])); \
    _Pragma("unroll") \
    for (int n = 0; n < 4; n++) \
      bfr[n] = __builtin_bit_cast(bf16x8, *(const uint4*)(&lds[(B)*12288 + bbase + n*512])); \
    __builtin_amdgcn_s_setprio(1); \
    _Pragma("unroll") \
    for (int m = 0; m < 4; m++) \
      _Pragma("unroll") \
      for (int n = 0; n < 4; n++) \
        acc[m][n] = __builtin_amdgcn_mfma_f32_16x16x32_bf16(af[m], bfr[n], acc[m][n], 0, 0, 0); \
    __builtin_amdgcn_s_setprio(0); \
    if ((VMW) == 3){ asm volatile("s_waitcnt vmcnt(3)" ::: "memory"); __builtin_amdgcn_s_barrier(); } \
    else if ((VMW) == 0){ asm volatile("s_waitcnt vmcnt(0)" ::: "memory"); __builtin_amdgcn_s_barrier(); } \
  }while(0)

  GSTAGE(0); GSTAGE(1);
  asm volatile("s_waitcnt vmcnt(3)" ::: "memory");
  __builtin_amdgcn_s_barrier();

  #pragma unroll 1
  for (int rr = 0; rr < 10; rr++){
    GBODY(0, 1, 3);
    GBODY(1, 1, 3);
    GBODY(2, 1, 3);
  }
  GBODY(0, 0, 0);
  GBODY(1, 0, -1);

#undef GBODY
#undef GSTAGE

  #pragma unroll
  for (int m = 0; m < 4; m++){
    const size_t i0 = arow0 + wr*64 + m*16 + g*4;
    #pragma unroll
    for (int n = 0; n < 4; n++){
      const int o = (int)brow0 + wc*64 + n*16 + c16;
      const float bias_v = bias[o];
      if (MODE == 0){
        const int proj = o >> 10, wi = o & 1023, hh = wi >> 6, dd = wi & 63;
        if (proj < 2){
          u16* base = (proj == 0) ? q_ws : k_ws;
          const float sc = (proj == 0) ? QSCALE : 1.0f;
          #pragma unroll
          for (int r = 0; r < 4; r++){
            const size_t i = i0 + r;
            const size_t bb = i >> 11, nn = i & 2047;
            base[((bb*16 + hh)*2048 + nn)*64 + dd] = f2bf((acc[m][n][r] + bias_v)*sc);
          }
        } else {
          // V^T in bijection-order: n' = (nn & ~31) | ((nn>>4)&1)<<2 | ((nn>>2)&3)<<3
          const size_t bb = i0 >> 11;
          const uint32_t nn = (uint32_t)(i0 & 2047);
          const uint32_t nnp = (nn & ~31u) | (((nn >> 4) & 1u) << 2) | (((nn >> 2) & 3u) << 3);
          union{ u16 u[4]; uint64_t v; } pk;
          #pragma unroll
          for (int r = 0; r < 4; r++) pk.u[r] = f2bf(acc[m][n][r] + bias_v);
          *reinterpret_cast<uint64_t*>(v_ws + ((bb*16 + hh)*64 + dd)*2048 + nnp) = pk.v;
        }
      } else {
        #pragma unroll
        for (int r = 0; r < 4; r++)
          Cout[(i0 + r)*1024 + o] = acc[m][n][r] + bias_v;
      }
    }
  }
}

// ---------------- flash attention: 4-ring, paired tiles; V reads single b128 ----------------
__global__ __launch_bounds__(256, 2) void attn_k(
    const u16* __restrict__ Q, const u16* __restrict__ Kb, const u16* __restrict__ Vt,
    u16* __restrict__ O)
{
  __shared__ u16 lds[4*8192];   // [buf:4][ K:4096 | V:4096 ], XOR-8 swizzled 16B slots
  const int tid = threadIdx.x, w = tid >> 6, lane = tid & 63;
  const int g = lane >> 4, l16 = lane & 15;

  const int f   = ((blockIdx.x & 7) << 6) | (blockIdx.x >> 3);
  const int qt_ = f & 7, bh = f >> 3;
  const int b = bh >> 4, h = bh & 15;
  const size_t hb = (size_t)bh * 2048 * 64;

  const int qrow0 = qt_*256 + w*64 + l16;
  bf16x8 qf[4][2];
  #pragma unroll
  for (int qt = 0; qt < 4; qt++)
    #pragma unroll
    for (int kc = 0; kc < 2; kc++)
      qf[qt][kc] = __builtin_bit_cast(bf16x8,
        *(const uint4*)(Q + hb + (size_t)(qrow0 + qt*16)*64 + kc*32 + g*8));

  f32x4 acc[4][4] = {};
  f32x4 lacc[4] = {};

  union{ u16 u[8]; bf16x8 f; } one_;
  #pragma unroll
  for (int i = 0; i < 8; i++) one_.u[i] = 0x3F80;
  const bf16x8 onesv = one_.f;

  const int srowL = w*8 + (lane >> 3);
  const int schunk = ((lane & 7) ^ ((lane >> 3) & 7)) * 8;
  const u16* gKs = Kb + hb + (size_t)srowL*64   + schunk;
  const u16* gVs = Vt + hb + (size_t)srowL*2048 + schunk;

  u16* ldsK0 = &lds[w*512];
  u16* ldsV0 = &lds[4096 + w*512];

  const int kb0 = l16*64 + (g ^ (l16 & 7))*8;
  const int kb1 = kb0 ^ 32;
  // V fragment (bijection-order layout): single b128 at chunk (p*4+g)^(l16&7)
  int vbp[2];
  #pragma unroll
  for (int p = 0; p < 2; p++)
    vbp[p] = l16*64 + (((p*4 + g) ^ (l16 & 7)) << 3);

#define STAGE_T(B2) do{ \
    GLD_LDS16(gKs,          ldsK0 + (B2)*8192); \
    GLD_LDS16(gKs + 2048,   ldsK0 + (B2)*8192 + 2048); \
    GLD_LDS16(gVs,          ldsV0 + (B2)*8192); \
    GLD_LDS16(gVs + 65536,  ldsV0 + (B2)*8192 + 2048); \
    gKs += 4096; gVs += 64; \
  }while(0)

#define TILE_T(B) do{ \
    _Pragma("unroll") \
    for (int p = 0; p < 2; p++){ \
      uint32_t pklo[2][4], pkhi[2][4]; \
      _Pragma("unroll") \
      for (int jh = 0; jh < 2; jh++){ \
        const int jt = p*2 + jh; \
        bf16x8 kf0 = __builtin_bit_cast(bf16x8, *(const uint4*)(&lds[(B)*8192 + jt*1024] + kb0)); \
        bf16x8 kf1 = __builtin_bit_cast(bf16x8, *(const uint4*)(&lds[(B)*8192 + jt*1024] + kb1)); \
        _Pragma("unroll") \
        for (int qt = 0; qt < 4; qt++){ \
          f32x4 st = {0.f,0.f,0.f,0.f}; \
          st = __builtin_amdgcn_mfma_f32_16x16x32_bf16(kf0, qf[qt][0], st, 0, 0, 0); \
          st = __builtin_amdgcn_mfma_f32_16x16x32_bf16(kf1, qf[qt][1], st, 0, 0, 0); \
          const uint32_t y0 = __float_as_uint(fmaf(st[0], 128.f, EXPMAGIC)); \
          const uint32_t y1 = __float_as_uint(fmaf(st[1], 128.f, EXPMAGIC)); \
          const uint32_t y2 = __float_as_uint(fmaf(st[2], 128.f, EXPMAGIC)); \
          const uint32_t y3 = __float_as_uint(fmaf(st[3], 128.f, EXPMAGIC)); \
          pklo[jh][qt] = __builtin_amdgcn_perm(y1, y0, 0x05040100u); \
          pkhi[jh][qt] = __builtin_amdgcn_perm(y3, y2, 0x05040100u); \
        } \
      } \
      union { uint32_t u[4]; bf16x8 f; } pf[4]; \
      _Pragma("unroll") \
      for (int qt = 0; qt < 4; qt++){ \
        pf[qt].u[0] = pklo[0][qt]; pf[qt].u[1] = pkhi[0][qt]; \
        pf[qt].u[2] = pklo[1][qt]; pf[qt].u[3] = pkhi[1][qt]; \
      } \
      __builtin_amdgcn_s_setprio(1); \
      _Pragma("unroll") \
      for (int qt = 0; qt < 4; qt++) \
        lacc[qt] = __builtin_amdgcn_mfma_f32_16x16x32_bf16(onesv, pf[qt].f, lacc[qt], 0, 0, 0); \
      _Pragma("unroll") \
      for (int dt = 0; dt < 4; dt++){ \
        union { uint4 u4; bf16x8 f; } vf; \
        vf.u4 = *(const uint4*)(&lds[(B)*8192 + 4096 + dt*1024] + vbp[p]); \
        _Pragma("unroll") \
        for (int qt = 0; qt < 4; qt++) \
          acc[dt][qt] = __builtin_amdgcn_mfma_f32_16x16x32_bf16(vf.f, pf[qt].f, acc[dt][qt], 0, 0, 0); \
      } \
      __builtin_amdgcn_s_setprio(0); \
    } \
  }while(0)

#define PAIR_T(B0, B1, STG, SYNC) do{ \
    if (STG){ STAGE_T((B0)^2); STAGE_T((B1)^2); } \
    TILE_T(B0); \
    TILE_T(B1); \
    if (SYNC){ asm volatile("s_waitcnt vmcnt(0)" ::: "memory"); __builtin_amdgcn_s_barrier(); } \
  }while(0)

  STAGE_T(0); STAGE_T(1);
  asm volatile("s_waitcnt vmcnt(0)" ::: "memory");
  __builtin_amdgcn_s_barrier();

  #pragma unroll 1
  for (int rr = 0; rr < 7; rr++){
    PAIR_T(0, 1, 1, 1);
    PAIR_T(2, 3, 1, 1);
  }
  PAIR_T(0, 1, 1, 1);
  PAIR_T(2, 3, 0, 0);

#undef PAIR_T
#undef TILE_T
#undef STAGE_T

  float inv[4];
  #pragma unroll
  for (int qt = 0; qt < 4; qt++) inv[qt] = 1.f / lacc[qt][0];

  #pragma unroll
  for (int qt = 0; qt < 4; qt++){
    const size_t ob = (((size_t)(b*2048 + qrow0 + qt*16))*16 + h)*64;
    #pragma unroll
    for (int dt = 0; dt < 4; dt++){
      union{ u16 u[4]; uint64_t v; } pkk;
      #pragma unroll
      for (int r = 0; r < 4; r++) pkk.u[r] = f2bf(acc[dt][qt][r] * inv[qt]);
      *reinterpret_cast<uint64_t*>(O + ob + dt*16 + g*4) = pkk.v;
    }
  }
}

// ---------------- launch ----------------
extern "C" void kernel_launch(void* const* d_in, const int* in_sizes, int n_in,
                              void* d_out, int out_size, void* d_ws, size_t ws_size,
                              hipStream_t stream)
{
  const float* x  = (const float*)d_in[0];
  const float* Wq = (const float*)d_in[1];
  const float* bq = (const float*)d_in[2];
  const float* Wk = (const float*)d_in[3];
  const float* bk = (const float*)d_in[4];
  const float* Wv = (const float*)d_in[5];
  const float* bv = (const float*)d_in[6];
  const float* Wo = (const float*)d_in[7];
  const float* bo = (const float*)d_in[8];
  float* out = (float*)d_out;

  char* ws = (char*)d_ws;
  size_t off = 0;
  auto bump = [&](size_t bytes){ size_t o = off; off = (off + bytes + 255) & ~(size_t)255; return o; };
  u16*  xb   = (u16*)  (ws + bump(8388608ull*2));
  u16*  wqkv = (u16*)  (ws + bump(3145728ull*2));
  u16*  wob  = (u16*)  (ws + bump(1048576ull*2));
  float* bqkv= (float*)(ws + bump(3072ull*4));
  u16*  qws  = (u16*)  (ws + bump(8388608ull*2));
  u16*  kws  = (u16*)  (ws + bump(8388608ull*2));
  u16*  vws  = (u16*)  (ws + bump(8388608ull*2));
  u16*  att  = (u16*)  (ws + bump(8388608ull*2));

  k_prep<<<2048, 256, 0, stream>>>(
      (const float4*)x, (const float4*)Wq, (const float4*)Wk, (const float4*)Wv, (const float4*)Wo,
      (const float4*)bq, (const float4*)bk, (const float4*)bv,
      (uint64_t*)xb, (uint64_t*)wqkv, (uint64_t*)wob, (float4*)bqkv);

  gemm128x256<0><<<768, 512, 0, stream>>>(xb, wqkv, bqkv, nullptr, qws, kws, vws);
  attn_k<<<512, 256, 0, stream>>>(qws, kws, vws, att);
  gemm128x256<1><<<256, 512, 0, stream>>>(att, wob, bo, out, nullptr, nullptr, nullptr);
}